// Round 1
// baseline (231.142 us; speedup 1.0000x reference)
//
#include <hip/hip_runtime.h>

#define NB 64      // batch
#define SEQ 305    // sequence length
#define DIM 2048   // hidden
#define NP 256     // patches
#define NT 48      // task tokens (305 - 257)
#define NKEEP 128  // kept patches
#define SOUT 177   // 1 + 128 + 48

static_assert(1 + NP + NT == SEQ, "layout");

constexpr float kScale = 0.022097086912079608f;  // 1/sqrt(2048)

// ---------------------------------------------------------------------------
// K1: per (b, 64-patch tile): raw dots R[64p][48t] = patch . task (fp32),
// fused row sum-of-squares (rms), softmax -> attn' = softmax * invT,
// Rn = raw * invP. Also zero-inits the umax argmax keys for this p-range.
// ---------------------------------------------------------------------------
__global__ __launch_bounds__(256) void k1_gemm_softmax(
    const float* __restrict__ tokens, float* __restrict__ attnp,
    float* __restrict__ rn, unsigned long long* __restrict__ umax) {
  const int pt = blockIdx.x;  // 0..3 patch tile
  const int b = blockIdx.y;   // 0..63
  const int t = threadIdx.x;  // 0..255

  __shared__ float pC[32][68];  // [d][patch-row], stride 68: 16B-aligned b128, low conflict
  __shared__ float tC[32][49];  // [d][task-row]
  __shared__ float L[64][49];   // raw dot tile
  __shared__ float invPs[64];
  __shared__ float invTs[48];
  __shared__ float ssqP[64];
  __shared__ float ssqT[48];

  if (t < 64) umax[(size_t)b * NP + pt * 64 + t] = 0ull;

  const float* pbase = tokens + ((size_t)b * SEQ + 1 + pt * 64) * DIM;
  const float* tbase = tokens + ((size_t)b * SEQ + 1 + NP) * DIM;

  const int tp = t >> 4;    // 0..15 -> p = tp*4 + i
  const int tq = t & 15;    // 0..15 -> tt = tq*3 + j
  const int srow = t >> 3;  // staging row 0..31
  const int sc4 = t & 7;    // staging f4 col

  float accA[4][3] = {};
  float accB[4][3] = {};
  float ssq0 = 0.f, ssq1 = 0.f, ssqt0 = 0.f, ssqt1 = 0.f;

  for (int dc = 0; dc < DIM; dc += 32) {
    // issue global loads before barrier (overlap with previous compute)
    float4 a0 = *(const float4*)(pbase + (size_t)srow * DIM + dc + sc4 * 4);
    float4 a1 = *(const float4*)(pbase + (size_t)(srow + 32) * DIM + dc + sc4 * 4);
    float4 b0, b1;
    if (t < 192) {
      b0 = *(const float4*)(tbase + (size_t)srow * DIM + dc + sc4 * 4);
      b1 = *(const float4*)(tbase + (size_t)(srow + 24) * DIM + dc + sc4 * 4);
    }
    __syncthreads();  // previous compute done reading LDS
    pC[sc4 * 4 + 0][srow] = a0.x;
    pC[sc4 * 4 + 1][srow] = a0.y;
    pC[sc4 * 4 + 2][srow] = a0.z;
    pC[sc4 * 4 + 3][srow] = a0.w;
    pC[sc4 * 4 + 0][srow + 32] = a1.x;
    pC[sc4 * 4 + 1][srow + 32] = a1.y;
    pC[sc4 * 4 + 2][srow + 32] = a1.z;
    pC[sc4 * 4 + 3][srow + 32] = a1.w;
    ssq0 += a0.x * a0.x + a0.y * a0.y + a0.z * a0.z + a0.w * a0.w;
    ssq1 += a1.x * a1.x + a1.y * a1.y + a1.z * a1.z + a1.w * a1.w;
    if (t < 192) {
      tC[sc4 * 4 + 0][srow] = b0.x;
      tC[sc4 * 4 + 1][srow] = b0.y;
      tC[sc4 * 4 + 2][srow] = b0.z;
      tC[sc4 * 4 + 3][srow] = b0.w;
      tC[sc4 * 4 + 0][srow + 24] = b1.x;
      tC[sc4 * 4 + 1][srow + 24] = b1.y;
      tC[sc4 * 4 + 2][srow + 24] = b1.z;
      tC[sc4 * 4 + 3][srow + 24] = b1.w;
      ssqt0 += b0.x * b0.x + b0.y * b0.y + b0.z * b0.z + b0.w * b0.w;
      ssqt1 += b1.x * b1.x + b1.y * b1.y + b1.z * b1.z + b1.w * b1.w;
    }
    __syncthreads();
#pragma unroll
    for (int dd = 0; dd < 32; ++dd) {
      float4 pv = *(const float4*)&pC[dd][tp * 4];
      float pa[4] = {pv.x, pv.y, pv.z, pv.w};
      float tv[3] = {tC[dd][tq * 3 + 0], tC[dd][tq * 3 + 1], tC[dd][tq * 3 + 2]};
      if (dd & 1) {
#pragma unroll
        for (int i = 0; i < 4; ++i)
#pragma unroll
          for (int j = 0; j < 3; ++j) accB[i][j] += pa[i] * tv[j];
      } else {
#pragma unroll
        for (int i = 0; i < 4; ++i)
#pragma unroll
          for (int j = 0; j < 3; ++j) accA[i][j] += pa[i] * tv[j];
      }
    }
  }

  // reduce sum-of-squares across the 8 staging lanes of each row
  for (int o = 4; o >= 1; o >>= 1) {
    ssq0 += __shfl_down(ssq0, o, 8);
    ssq1 += __shfl_down(ssq1, o, 8);
    ssqt0 += __shfl_down(ssqt0, o, 8);
    ssqt1 += __shfl_down(ssqt1, o, 8);
  }
  if (sc4 == 0) {
    ssqP[srow] = ssq0;
    ssqP[srow + 32] = ssq1;
    if (t < 192) {
      ssqT[srow] = ssqt0;
      ssqT[srow + 24] = ssqt1;
    }
  }
  __syncthreads();
  if (t < 64) {
    invPs[t] = 1.0f / sqrtf(ssqP[t] * (1.0f / 2048.0f) + 1e-6f);
  } else if (t < 112) {
    invTs[t - 64] = 1.0f / sqrtf(ssqT[t - 64] * (1.0f / 2048.0f) + 1e-6f);
  }
// write raw dots
#pragma unroll
  for (int i = 0; i < 4; ++i)
#pragma unroll
    for (int j = 0; j < 3; ++j) L[tp * 4 + i][tq * 3 + j] = accA[i][j] + accB[i][j];
  __syncthreads();

  if (t < 64) {
    const float invp = invPs[t];
    float lg[48];
    float m = -3.4e38f;
#pragma unroll
    for (int j = 0; j < 48; ++j) {
      lg[j] = L[t][j] * invp * invTs[j] * kScale;
      m = fmaxf(m, lg[j]);
    }
    float s = 0.f;
#pragma unroll
    for (int j = 0; j < 48; ++j) {
      lg[j] = expf(lg[j] - m);
      s += lg[j];
    }
    const float is = 1.0f / s;
    float* ao = attnp + ((size_t)b * NP + pt * 64 + t) * NT;
    float* ro = rn + ((size_t)b * NP + pt * 64 + t) * NT;
#pragma unroll
    for (int j = 0; j < 48; ++j) ao[j] = lg[j] * is * invTs[j];
#pragma unroll
    for (int j = 0; j < 48; ++j) ro[j] = L[t][j] * invp;
  }
}

// ---------------------------------------------------------------------------
// K2: score[p][q] = sum_t attn'[p][t] * Rn[q][t]  (K=48 GEMM, 64x64 tile),
// running argmax over q folded in via packed (mono-float | ~q) atomicMax.
// Skipping queries-rms and 1/sqrt(D): positive per-p scalars, argmax-safe.
// ---------------------------------------------------------------------------
__global__ __launch_bounds__(256) void k2_score_argmax(
    const float* __restrict__ attnp, const float* __restrict__ rn,
    unsigned long long* __restrict__ umax) {
  const int b = blockIdx.y;
  const int qt = blockIdx.x & 3;
  const int pb = blockIdx.x >> 2;
  const int t = threadIdx.x;
  const int tp = t >> 4, tq = t & 15;

  __shared__ float aS[48][68];  // [k][p-local]
  __shared__ float rS[48][68];  // [k][q-local]

  const float* ab = attnp + ((size_t)b * NP + pb * 64) * NT;
  const float* rb = rn + ((size_t)b * NP + qt * 64) * NT;
#pragma unroll
  for (int l = 0; l < 3; ++l) {
    int u = t + 256 * l;  // 0..767 -> 64 rows x 12 f4
    int row = u / 12, c4 = u % 12;
    float4 v = *(const float4*)(ab + (size_t)row * NT + c4 * 4);
    aS[c4 * 4 + 0][row] = v.x;
    aS[c4 * 4 + 1][row] = v.y;
    aS[c4 * 4 + 2][row] = v.z;
    aS[c4 * 4 + 3][row] = v.w;
    float4 w = *(const float4*)(rb + (size_t)row * NT + c4 * 4);
    rS[c4 * 4 + 0][row] = w.x;
    rS[c4 * 4 + 1][row] = w.y;
    rS[c4 * 4 + 2][row] = w.z;
    rS[c4 * 4 + 3][row] = w.w;
  }
  __syncthreads();

  float acc[4][4] = {};
#pragma unroll
  for (int k = 0; k < 48; ++k) {
    float4 av = *(const float4*)&aS[k][tp * 4];
    float4 rv = *(const float4*)&rS[k][tq * 4];
    float aa[4] = {av.x, av.y, av.z, av.w};
    float rr[4] = {rv.x, rv.y, rv.z, rv.w};
#pragma unroll
    for (int i = 0; i < 4; ++i)
#pragma unroll
      for (int j = 0; j < 4; ++j) acc[i][j] += aa[i] * rr[j];
  }

#pragma unroll
  for (int i = 0; i < 4; ++i) {
    float bs = acc[i][0];
    int bq = qt * 64 + tq * 4;
#pragma unroll
    for (int j = 1; j < 4; ++j) {
      float s = acc[i][j];
      int q = qt * 64 + tq * 4 + j;
      if (s > bs) {  // strict > keeps smallest q on ties (first occurrence)
        bs = s;
        bq = q;
      }
    }
    unsigned us = __float_as_uint(bs);
    us = (us & 0x80000000u) ? ~us : (us | 0x80000000u);  // monotone float->uint
    unsigned long long key =
        ((unsigned long long)us << 32) | (unsigned long long)(0xFFFFFFFFu - (unsigned)bq);
    // reduce across the 16 tq lanes sharing these p-rows
    for (int o = 8; o >= 1; o >>= 1) {
      unsigned long long ok = __shfl_xor(key, o, 16);
      if (ok > key) key = ok;
    }
    if (tq == 0) atomicMax(&umax[(size_t)b * NP + pb * 64 + tp * 4 + i], key);
  }
}

// ---------------------------------------------------------------------------
// K3: per batch: decode argmax q, vote counts, exact rank (count desc, index
// asc), keep rank<128, emit kept indices in ascending order.
// ---------------------------------------------------------------------------
__global__ __launch_bounds__(256) void k3_select(
    const unsigned long long* __restrict__ umax, int* __restrict__ order) {
  const int b = blockIdx.x, t = threadIdx.x;
  __shared__ int cnt[256];
  __shared__ int kept[256];
  cnt[t] = 0;
  __syncthreads();
  unsigned long long key = umax[(size_t)b * NP + t];
  int q = (int)(0xFFFFFFFFu - (unsigned)(key & 0xFFFFFFFFull));
  atomicAdd(&cnt[q], 1);
  __syncthreads();
  const int c = cnt[t];
  int rank = 0;
  for (int u = 0; u < 256; ++u) {
    int cu = cnt[u];
    rank += (cu > c || (cu == c && u < t)) ? 1 : 0;
  }
  kept[t] = (rank < NKEEP) ? 1 : 0;
  __syncthreads();
  if (kept[t]) {
    int pos = 0;
    for (int u = 0; u < t; ++u) pos += kept[u];
    order[b * NKEEP + pos] = t;
  }
}

// ---------------------------------------------------------------------------
// K4/K5: gather rows (exact copies) into the packed output.
// ---------------------------------------------------------------------------
__device__ __forceinline__ int src_row(int s, int b, const int* order) {
  if (s == 0) return 0;
  if (s < 1 + NKEEP) return 1 + order[b * NKEEP + (s - 1)];
  return s + (NP - NKEEP);  // s+128 -> task rows 257..304
}

__global__ __launch_bounds__(256) void k4_gather_tokens(
    const float* __restrict__ tokens, const int* __restrict__ order,
    float* __restrict__ out) {
  const int s = blockIdx.x;  // 0..176
  const int b = blockIdx.y;
  const int t = threadIdx.x;
  const int src = src_row(s, b, order);
  const float4* in4 = (const float4*)(tokens + ((size_t)b * SEQ + src) * DIM);
  float4* o4 = (float4*)(out + ((size_t)b * SOUT + s) * DIM);
  o4[t] = in4[t];
  o4[t + 256] = in4[t + 256];
}

__global__ __launch_bounds__(192) void k5_gather_meta(
    const int* __restrict__ pos, const int* __restrict__ msk,
    const int* __restrict__ order, float* __restrict__ out1,
    float* __restrict__ out2) {
  const int b = blockIdx.x;
  const int s = threadIdx.x;
  if (s >= SOUT) return;
  const int src = src_row(s, b, order);
  out1[b * SOUT + s] = (float)pos[b * SEQ + src];
  out2[b * SOUT + s] = (float)msk[b * SEQ + src];
}

// ---------------------------------------------------------------------------
extern "C" void kernel_launch(void* const* d_in, const int* in_sizes, int n_in,
                              void* d_out, int out_size, void* d_ws,
                              size_t ws_size, hipStream_t stream) {
  const float* tokens = (const float*)d_in[0];
  const int* pos = (const int*)d_in[1];
  const int* msk = (const int*)d_in[2];

  float* out0 = (float*)d_out;                       // tokens_out (B,177,2048)
  float* out1 = out0 + (size_t)NB * SOUT * DIM;      // pos_out (B,177) as float
  float* out2 = out1 + (size_t)NB * SOUT;            // mask_out (B,177) as float

  char* ws = (char*)d_ws;
  float* attnp = (float*)ws;                              // B*256*48 floats
  float* rn = attnp + (size_t)NB * NP * NT;               // B*256*48 floats
  unsigned long long* umax =
      (unsigned long long*)(ws + (size_t)2 * NB * NP * NT * sizeof(float));
  int* order = (int*)((char*)umax + (size_t)NB * NP * sizeof(unsigned long long));

  k1_gemm_softmax<<<dim3(4, NB), 256, 0, stream>>>(tokens, attnp, rn, umax);
  k2_score_argmax<<<dim3(16, NB), 256, 0, stream>>>(attnp, rn, umax);
  k3_select<<<NB, 256, 0, stream>>>(umax, order);
  k4_gather_tokens<<<dim3(SOUT, NB), 256, 0, stream>>>(tokens, order, out0);
  k5_gather_meta<<<NB, 192, 0, stream>>>(pos, msk, order, out1, out2);
}

// Round 2
// 191.387 us; speedup vs baseline: 1.2077x; 1.2077x over previous
//
#include <hip/hip_runtime.h>

#define NB 64      // batch
#define SEQ 305    // sequence length
#define DIM 2048   // hidden
#define NP 256     // patches
#define NT 48      // task tokens (305 - 257)
#define NKEEP 128  // kept patches
#define SOUT 177   // 1 + 128 + 48
#define NDC 4      // D split-K chunks
#define DCHUNK 512 // DIM / NDC

static_assert(1 + NP + NT == SEQ, "layout");

constexpr float kScale = 0.022097086912079608f;  // 1/sqrt(2048)

// ---------------------------------------------------------------------------
// K1a: split-K partial GEMM. grid (16 = 4 dci x 4 pt, 64 b).
// Computes partial R[64p][48t] over d in [dci*512, dci*512+512) plus partial
// sum-of-squares. Deterministic (fixed reduction order in K1b).
// ---------------------------------------------------------------------------
__global__ __launch_bounds__(256) void k1a_partial_gemm(
    const float* __restrict__ tokens, float* __restrict__ rpart,
    float* __restrict__ ssqPpart, float* __restrict__ ssqTpart) {
  const int pt = blockIdx.x & 3;   // patch tile 0..3
  const int dci = blockIdx.x >> 2; // D chunk 0..3
  const int b = blockIdx.y;        // 0..63
  const int t = threadIdx.x;       // 0..255

  __shared__ float pC[32][68];  // [d][patch-row]
  __shared__ float tC[32][49];  // [d][task-row]

  const float* pbase = tokens + ((size_t)b * SEQ + 1 + pt * 64) * DIM + dci * DCHUNK;
  const float* tbase = tokens + ((size_t)b * SEQ + 1 + NP) * DIM + dci * DCHUNK;

  const int tp = t >> 4;    // 0..15 -> p = tp*4 + i
  const int tq = t & 15;    // 0..15 -> tt = tq*3 + j
  const int srow = t >> 3;  // staging row 0..31
  const int sc4 = t & 7;    // staging f4 col

  float accA[4][3] = {};
  float accB[4][3] = {};
  float ssq0 = 0.f, ssq1 = 0.f, ssqt0 = 0.f, ssqt1 = 0.f;

  for (int dc = 0; dc < DCHUNK; dc += 32) {
    float4 a0 = *(const float4*)(pbase + (size_t)srow * DIM + dc + sc4 * 4);
    float4 a1 = *(const float4*)(pbase + (size_t)(srow + 32) * DIM + dc + sc4 * 4);
    float4 b0, b1;
    if (t < 192) {
      b0 = *(const float4*)(tbase + (size_t)srow * DIM + dc + sc4 * 4);
      b1 = *(const float4*)(tbase + (size_t)(srow + 24) * DIM + dc + sc4 * 4);
    }
    __syncthreads();
    pC[sc4 * 4 + 0][srow] = a0.x;
    pC[sc4 * 4 + 1][srow] = a0.y;
    pC[sc4 * 4 + 2][srow] = a0.z;
    pC[sc4 * 4 + 3][srow] = a0.w;
    pC[sc4 * 4 + 0][srow + 32] = a1.x;
    pC[sc4 * 4 + 1][srow + 32] = a1.y;
    pC[sc4 * 4 + 2][srow + 32] = a1.z;
    pC[sc4 * 4 + 3][srow + 32] = a1.w;
    ssq0 += a0.x * a0.x + a0.y * a0.y + a0.z * a0.z + a0.w * a0.w;
    ssq1 += a1.x * a1.x + a1.y * a1.y + a1.z * a1.z + a1.w * a1.w;
    if (t < 192) {
      tC[sc4 * 4 + 0][srow] = b0.x;
      tC[sc4 * 4 + 1][srow] = b0.y;
      tC[sc4 * 4 + 2][srow] = b0.z;
      tC[sc4 * 4 + 3][srow] = b0.w;
      tC[sc4 * 4 + 0][srow + 24] = b1.x;
      tC[sc4 * 4 + 1][srow + 24] = b1.y;
      tC[sc4 * 4 + 2][srow + 24] = b1.z;
      tC[sc4 * 4 + 3][srow + 24] = b1.w;
      ssqt0 += b0.x * b0.x + b0.y * b0.y + b0.z * b0.z + b0.w * b0.w;
      ssqt1 += b1.x * b1.x + b1.y * b1.y + b1.z * b1.z + b1.w * b1.w;
    }
    __syncthreads();
#pragma unroll
    for (int dd = 0; dd < 32; ++dd) {
      float4 pv = *(const float4*)&pC[dd][tp * 4];
      float pa[4] = {pv.x, pv.y, pv.z, pv.w};
      float tv[3] = {tC[dd][tq * 3 + 0], tC[dd][tq * 3 + 1], tC[dd][tq * 3 + 2]};
      if (dd & 1) {
#pragma unroll
        for (int i = 0; i < 4; ++i)
#pragma unroll
          for (int j = 0; j < 3; ++j) accB[i][j] += pa[i] * tv[j];
      } else {
#pragma unroll
        for (int i = 0; i < 4; ++i)
#pragma unroll
          for (int j = 0; j < 3; ++j) accA[i][j] += pa[i] * tv[j];
      }
    }
  }

  // partial dot tile -> workspace: rpart[((b*4+dci)*4+pt)][64][48]
  float* rp = rpart + (((size_t)b * NDC + dci) * 4 + pt) * (64 * NT);
#pragma unroll
  for (int i = 0; i < 4; ++i)
#pragma unroll
    for (int j = 0; j < 3; ++j)
      rp[(tp * 4 + i) * NT + tq * 3 + j] = accA[i][j] + accB[i][j];

  // partial sum-of-squares across the 8 staging lanes of each row
  for (int o = 4; o >= 1; o >>= 1) {
    ssq0 += __shfl_down(ssq0, o, 8);
    ssq1 += __shfl_down(ssq1, o, 8);
    ssqt0 += __shfl_down(ssqt0, o, 8);
    ssqt1 += __shfl_down(ssqt1, o, 8);
  }
  if (sc4 == 0) {
    float* sp = ssqPpart + (((size_t)b * NDC + dci) * 4 + pt) * 64;
    sp[srow] = ssq0;
    sp[srow + 32] = ssq1;
    if (pt == 0 && t < 192) {
      float* st = ssqTpart + ((size_t)b * NDC + dci) * NT;
      st[srow] = ssqt0;
      st[srow + 24] = ssqt1;
    }
  }
}

// ---------------------------------------------------------------------------
// K1b: sum the 4 split-K partials (fixed order -> deterministic), fused
// rms + softmax -> attn' = softmax*invT, Rn = raw*invP. Inits umax.
// grid (4 pt, 64 b), 256 threads.
// ---------------------------------------------------------------------------
__global__ __launch_bounds__(256) void k1b_reduce_softmax(
    const float* __restrict__ rpart, const float* __restrict__ ssqPpart,
    const float* __restrict__ ssqTpart, float* __restrict__ attnp,
    float* __restrict__ rn, unsigned long long* __restrict__ umax) {
  const int pt = blockIdx.x;
  const int b = blockIdx.y;
  const int t = threadIdx.x;

  __shared__ float L[64 * 49];
  __shared__ float invPs[64];
  __shared__ float invTs[48];

  if (t < 64) umax[(size_t)b * NP + pt * 64 + t] = 0ull;

  // sum R partials: 3072 elements, 12 per thread, fixed dci order
  const float* rp0 = rpart + (((size_t)b * NDC) * 4 + pt) * (64 * NT);
#pragma unroll
  for (int l = 0; l < 12; ++l) {
    int e = t + 256 * l;
    float s = rp0[e] + rp0[e + 4 * 64 * NT] + rp0[e + 8 * 64 * NT] + rp0[e + 12 * 64 * NT];
    L[(e / NT) * 49 + (e % NT)] = s;
  }
  if (t < 64) {
    const float* sp = ssqPpart + (((size_t)b * NDC) * 4 + pt) * 64;
    float s = sp[t] + sp[t + 4 * 64] + sp[t + 8 * 64] + sp[t + 12 * 64];
    invPs[t] = 1.0f / sqrtf(s * (1.0f / 2048.0f) + 1e-6f);
  } else if (t < 112) {
    const float* st = ssqTpart + ((size_t)b * NDC) * NT;
    int j = t - 64;
    float s = st[j] + st[j + NT] + st[j + 2 * NT] + st[j + 3 * NT];
    invTs[j] = 1.0f / sqrtf(s * (1.0f / 2048.0f) + 1e-6f);
  }
  __syncthreads();

  if (t < 64) {
    const float invp = invPs[t];
    float lg[48];
    float m = -3.4e38f;
#pragma unroll
    for (int j = 0; j < 48; ++j) {
      lg[j] = L[t * 49 + j] * invp * invTs[j] * kScale;
      m = fmaxf(m, lg[j]);
    }
    float s = 0.f;
#pragma unroll
    for (int j = 0; j < 48; ++j) {
      lg[j] = expf(lg[j] - m);
      s += lg[j];
    }
    const float is = 1.0f / s;
    float* ao = attnp + ((size_t)b * NP + pt * 64 + t) * NT;
    float* ro = rn + ((size_t)b * NP + pt * 64 + t) * NT;
#pragma unroll
    for (int j = 0; j < 48; ++j) ao[j] = lg[j] * is * invTs[j];
#pragma unroll
    for (int j = 0; j < 48; ++j) ro[j] = L[t * 49 + j] * invp;
  }
}

// ---------------------------------------------------------------------------
// K2: score[p][q] = sum_t attn'[p][t] * Rn[q][t]  (K=48 GEMM, 64x64 tile),
// running argmax over q folded in via packed (mono-float | ~q) atomicMax.
// ---------------------------------------------------------------------------
__global__ __launch_bounds__(256) void k2_score_argmax(
    const float* __restrict__ attnp, const float* __restrict__ rn,
    unsigned long long* __restrict__ umax) {
  const int b = blockIdx.y;
  const int qt = blockIdx.x & 3;
  const int pb = blockIdx.x >> 2;
  const int t = threadIdx.x;
  const int tp = t >> 4, tq = t & 15;

  __shared__ float aS[48][68];
  __shared__ float rS[48][68];

  const float* ab = attnp + ((size_t)b * NP + pb * 64) * NT;
  const float* rb = rn + ((size_t)b * NP + qt * 64) * NT;
#pragma unroll
  for (int l = 0; l < 3; ++l) {
    int u = t + 256 * l;  // 0..767 -> 64 rows x 12 f4
    int row = u / 12, c4 = u % 12;
    float4 v = *(const float4*)(ab + (size_t)row * NT + c4 * 4);
    aS[c4 * 4 + 0][row] = v.x;
    aS[c4 * 4 + 1][row] = v.y;
    aS[c4 * 4 + 2][row] = v.z;
    aS[c4 * 4 + 3][row] = v.w;
    float4 w = *(const float4*)(rb + (size_t)row * NT + c4 * 4);
    rS[c4 * 4 + 0][row] = w.x;
    rS[c4 * 4 + 1][row] = w.y;
    rS[c4 * 4 + 2][row] = w.z;
    rS[c4 * 4 + 3][row] = w.w;
  }
  __syncthreads();

  float acc[4][4] = {};
#pragma unroll
  for (int k = 0; k < 48; ++k) {
    float4 av = *(const float4*)&aS[k][tp * 4];
    float4 rv = *(const float4*)&rS[k][tq * 4];
    float aa[4] = {av.x, av.y, av.z, av.w};
    float rr[4] = {rv.x, rv.y, rv.z, rv.w};
#pragma unroll
    for (int i = 0; i < 4; ++i)
#pragma unroll
      for (int j = 0; j < 4; ++j) acc[i][j] += aa[i] * rr[j];
  }

#pragma unroll
  for (int i = 0; i < 4; ++i) {
    float bs = acc[i][0];
    int bq = qt * 64 + tq * 4;
#pragma unroll
    for (int j = 1; j < 4; ++j) {
      float s = acc[i][j];
      int q = qt * 64 + tq * 4 + j;
      if (s > bs) {
        bs = s;
        bq = q;
      }
    }
    unsigned us = __float_as_uint(bs);
    us = (us & 0x80000000u) ? ~us : (us | 0x80000000u);
    unsigned long long key =
        ((unsigned long long)us << 32) | (unsigned long long)(0xFFFFFFFFu - (unsigned)bq);
    for (int o = 8; o >= 1; o >>= 1) {
      unsigned long long ok = __shfl_xor(key, o, 16);
      if (ok > key) key = ok;
    }
    if (tq == 0) atomicMax(&umax[(size_t)b * NP + pb * 64 + tp * 4 + i], key);
  }
}

// ---------------------------------------------------------------------------
// K3: per batch: decode argmax q, vote counts, exact rank, keep rank<128.
// ---------------------------------------------------------------------------
__global__ __launch_bounds__(256) void k3_select(
    const unsigned long long* __restrict__ umax, int* __restrict__ order) {
  const int b = blockIdx.x, t = threadIdx.x;
  __shared__ int cnt[256];
  __shared__ int kept[256];
  cnt[t] = 0;
  __syncthreads();
  unsigned long long key = umax[(size_t)b * NP + t];
  int q = (int)(0xFFFFFFFFu - (unsigned)(key & 0xFFFFFFFFull));
  atomicAdd(&cnt[q], 1);
  __syncthreads();
  const int c = cnt[t];
  int rank = 0;
  for (int u = 0; u < 256; ++u) {
    int cu = cnt[u];
    rank += (cu > c || (cu == c && u < t)) ? 1 : 0;
  }
  kept[t] = (rank < NKEEP) ? 1 : 0;
  __syncthreads();
  if (kept[t]) {
    int pos = 0;
    for (int u = 0; u < t; ++u) pos += kept[u];
    order[b * NKEEP + pos] = t;
  }
}

// ---------------------------------------------------------------------------
// K4/K5: gather rows (exact copies) into the packed output.
// ---------------------------------------------------------------------------
__device__ __forceinline__ int src_row(int s, int b, const int* order) {
  if (s == 0) return 0;
  if (s < 1 + NKEEP) return 1 + order[b * NKEEP + (s - 1)];
  return s + (NP - NKEEP);
}

__global__ __launch_bounds__(256) void k4_gather_tokens(
    const float* __restrict__ tokens, const int* __restrict__ order,
    float* __restrict__ out) {
  const int s = blockIdx.x;
  const int b = blockIdx.y;
  const int t = threadIdx.x;
  const int src = src_row(s, b, order);
  const float4* in4 = (const float4*)(tokens + ((size_t)b * SEQ + src) * DIM);
  float4* o4 = (float4*)(out + ((size_t)b * SOUT + s) * DIM);
  o4[t] = in4[t];
  o4[t + 256] = in4[t + 256];
}

__global__ __launch_bounds__(192) void k5_gather_meta(
    const int* __restrict__ pos, const int* __restrict__ msk,
    const int* __restrict__ order, float* __restrict__ out1,
    float* __restrict__ out2) {
  const int b = blockIdx.x;
  const int s = threadIdx.x;
  if (s >= SOUT) return;
  const int src = src_row(s, b, order);
  out1[b * SOUT + s] = (float)pos[b * SEQ + src];
  out2[b * SOUT + s] = (float)msk[b * SEQ + src];
}

// ---------------------------------------------------------------------------
extern "C" void kernel_launch(void* const* d_in, const int* in_sizes, int n_in,
                              void* d_out, int out_size, void* d_ws,
                              size_t ws_size, hipStream_t stream) {
  const float* tokens = (const float*)d_in[0];
  const int* pos = (const int*)d_in[1];
  const int* msk = (const int*)d_in[2];

  float* out0 = (float*)d_out;
  float* out1 = out0 + (size_t)NB * SOUT * DIM;
  float* out2 = out1 + (size_t)NB * SOUT;

  char* ws = (char*)d_ws;
  float* attnp = (float*)ws;                      // B*256*48
  float* rn = attnp + (size_t)NB * NP * NT;       // B*256*48
  unsigned long long* umax =
      (unsigned long long*)(rn + (size_t)NB * NP * NT);
  int* order = (int*)(umax + (size_t)NB * NP);
  float* rpart = (float*)(order + (size_t)NB * NKEEP);     // B*4*4*64*48
  float* ssqPpart = rpart + (size_t)NB * NDC * 4 * 64 * NT; // B*4*4*64
  float* ssqTpart = ssqPpart + (size_t)NB * NDC * 4 * 64;   // B*4*48

  k1a_partial_gemm<<<dim3(16, NB), 256, 0, stream>>>(tokens, rpart, ssqPpart, ssqTpart);
  k1b_reduce_softmax<<<dim3(4, NB), 256, 0, stream>>>(rpart, ssqPpart, ssqTpart,
                                                      attnp, rn, umax);
  k2_score_argmax<<<dim3(16, NB), 256, 0, stream>>>(attnp, rn, umax);
  k3_select<<<NB, 256, 0, stream>>>(umax, order);
  k4_gather_tokens<<<dim3(SOUT, NB), 256, 0, stream>>>(tokens, order, out0);
  k5_gather_meta<<<NB, 192, 0, stream>>>(pos, msk, order, out1, out2);
}